// Round 4
// baseline (301.202 us; speedup 1.0000x reference)
//
#include <hip/hip_runtime.h>

// Problem constants (fixed by setup_inputs)
#define B_SZ   8192
#define CH     5120          // C*H = 20*256
#define CH4    1280          // CH / 4
#define K_LAB  10
#define EPS    1e-8f
#define FLTMAX 3.402823466e38f

#define NTHR   256           // gather block (4 waves)
#define NCHUNK 5             // 5 * 256 thr * 4 cols = 5120 columns
#define PS     32            // sample sub-partitions per label
#define PF     8             // loads in flight per thread

// loss = sum_{k: n_k>0} (SSQ_k - ||S_k||^2/n_k + n_k*CH*eps^2) / (n_k*CH)
// (2*eps cross-term cancels exactly: sum_{b in k}(z_b - mu_k) == 0)

// ---------------------------------------------------------------------------
// Setup: stage labels in LDS (one coalesced pass), then per-label ascending
// index lists. Wave k handles label k (10 waves, 1 block).
__global__ __launch_bounds__(640) void codi_setup(
    const int* __restrict__ labels, int* __restrict__ idx,
    int* __restrict__ off, float* __restrict__ SSQ, float* __restrict__ nsq)
{
    __shared__ int lab_s[B_SZ];          // 32 KB
    __shared__ int cnts[K_LAB];
    __shared__ int offs[K_LAB + 1];
    const int tid  = threadIdx.x;
    const int k    = tid >> 6;           // wave index == label
    const int lane = tid & 63;

    // one coalesced global pass: 2048 int4 across 640 threads
    const int4* l4 = (const int4*)labels;
    for (int i = tid; i < B_SZ / 4; i += 640) ((int4*)lab_s)[i] = l4[i];
    __syncthreads();

    // pass 1: count label k (from LDS)
    int cnt = 0;
    for (int b0 = 0; b0 < B_SZ; b0 += 64)
        cnt += __popcll(__ballot(lab_s[b0 + lane] == k));
    if (lane == 0) cnts[k] = cnt;
    __syncthreads();
    if (tid == 0) {
        int a = 0;
        for (int j = 0; j < K_LAB; ++j) { offs[j] = a; a += cnts[j]; }
        offs[K_LAB] = a;
    }
    __syncthreads();

    // pass 2: scatter (ascending b within each label -> deterministic)
    int base = offs[k];
    const unsigned long long ltmask = (1ULL << lane) - 1ULL;
    for (int b0 = 0; b0 < B_SZ; b0 += 64) {
        int lab = lab_s[b0 + lane];
        unsigned long long m = __ballot(lab == k);
        if (lab == k) idx[base + __popcll(m & ltmask)] = b0 + lane;
        base += __popcll(m);
    }
    if (tid < K_LAB + 1) off[tid] = offs[tid];
    if (tid < K_LAB) { SSQ[tid] = 0.f; nsq[tid] = 0.f; }
}

// ---------------------------------------------------------------------------
// Main: block = (label k, column chunk, sample sub-range). Branch-free 8-deep
// load batches in the main loop; one conditional batch for the tail.
__global__ __launch_bounds__(NTHR) void codi_gather(
    const float4* __restrict__ z4, const int* __restrict__ idx,
    const int* __restrict__ off, float4* __restrict__ S_part,
    float* __restrict__ SSQ)
{
    const int tid   = threadIdx.x;
    const int k     = blockIdx.x / (NCHUNK * PS);
    const int rem   = blockIdx.x % (NCHUNK * PS);
    const int chunk = rem % NCHUNK;
    const int ps    = rem / NCHUNK;

    const int kb  = off[k];
    const int cnt = off[k + 1] - kb;
    const int s0  = kb + (int)(((long long)cnt * ps) / PS);
    const int s1  = kb + (int)(((long long)cnt * (ps + 1)) / PS);
    const int n   = s1 - s0;

    __shared__ int rows[288];            // worst case: ceil(8192/PS) = 256
    for (int i = tid; i < n; i += NTHR) rows[i] = idx[s0 + i];
    __syncthreads();

    const int col4 = chunk * NTHR + tid; // float4 column 0..1279
    float4 sum = make_float4(0.f, 0.f, 0.f, 0.f);
    float  ssq = 0.f;

#define SANITIZE(v) do { \
        v.x = (v.x == v.x) ? fminf(fmaxf(v.x, -FLTMAX), FLTMAX) : 0.f; \
        v.y = (v.y == v.y) ? fminf(fmaxf(v.y, -FLTMAX), FLTMAX) : 0.f; \
        v.z = (v.z == v.z) ? fminf(fmaxf(v.z, -FLTMAX), FLTMAX) : 0.f; \
        v.w = (v.w == v.w) ? fminf(fmaxf(v.w, -FLTMAX), FLTMAX) : 0.f; \
    } while (0)
#define ACCUM(v) do { \
        sum.x += v.x; sum.y += v.y; sum.z += v.z; sum.w += v.w; \
        ssq = fmaf(v.x, v.x, ssq); ssq = fmaf(v.y, v.y, ssq); \
        ssq = fmaf(v.z, v.z, ssq); ssq = fmaf(v.w, v.w, ssq); \
    } while (0)

    const int n_main = n & ~(PF - 1);
    for (int i0 = 0; i0 < n_main; i0 += PF) {
        float4 vb[PF];
        #pragma unroll
        for (int u = 0; u < PF; ++u)
            vb[u] = z4[(size_t)rows[i0 + u] * CH4 + col4];  // 8 indep dwordx4
        #pragma unroll
        for (int u = 0; u < PF; ++u) { SANITIZE(vb[u]); ACCUM(vb[u]); }
    }
    if (n_main < n) {                    // single conditional tail batch
        float4 vb[PF];
        #pragma unroll
        for (int u = 0; u < PF; ++u)
            if (n_main + u < n) vb[u] = z4[(size_t)rows[n_main + u] * CH4 + col4];
        #pragma unroll
        for (int u = 0; u < PF; ++u)
            if (n_main + u < n) { SANITIZE(vb[u]); ACCUM(vb[u]); }
    }
#undef SANITIZE
#undef ACCUM

    // private partial slice, written unconditionally (n may be 0)
    S_part[((size_t)(k * PS + ps)) * CH4 + col4] = sum;

    #pragma unroll
    for (int o = 32; o > 0; o >>= 1) ssq += __shfl_down(ssq, o, 64);
    if ((tid & 63) == 0) atomicAdd(&SSQ[k], ssq);
}

// ---------------------------------------------------------------------------
// Fold the PS partials straight into ||S_k||^2.
__global__ __launch_bounds__(NTHR) void codi_reduce(
    const float* __restrict__ S_part, float* __restrict__ nsq)
{
    const int i = blockIdx.x * NTHR + threadIdx.x;   // 0..51199
    const int k = i / CH;
    const int c = i - k * CH;
    float s = 0.f;
    #pragma unroll
    for (int ps = 0; ps < PS; ++ps)
        s += S_part[((size_t)(k * PS + ps)) * CH + c];
    float w = s * s;
    #pragma unroll
    for (int o = 32; o > 0; o >>= 1) w += __shfl_down(w, o, 64);
    if ((threadIdx.x & 63) == 0) atomicAdd(&nsq[k], w);  // CH%64==0 -> k uniform
}

__global__ __launch_bounds__(64) void codi_final(
    const int* __restrict__ off, const float* __restrict__ SSQ,
    const float* __restrict__ nsq, float* __restrict__ out)
{
    if (threadIdx.x == 0) {
        float loss = 0.f;
        for (int k = 0; k < K_LAB; ++k) {
            float n = (float)(off[k + 1] - off[k]);
            if (n > 0.f) {
                float sse = SSQ[k] - nsq[k] / n + n * (float)CH * (EPS * EPS);
                float mse = sse / (n * (float)CH);
                if (mse == mse) loss += mse;     // nan_to_num(mse_k)
            }
        }
        out[0] = loss;
    }
}

// ---------------------------------------------------------------------------
extern "C" void kernel_launch(void* const* d_in, const int* in_sizes, int n_in,
                              void* d_out, int out_size, void* d_ws, size_t ws_size,
                              hipStream_t stream) {
    const float4* z4     = (const float4*)d_in[0];
    const int*    labels = (const int*)d_in[1];

    // ws layout (floats): [0..9] SSQ, [16..25] nsq, [32..47] off[11],
    //                     [64..8255] idx[8192], [8256..] S_part[10][PS][5120]
    float* hdr    = (float*)d_ws;
    float* SSQ    = hdr;
    float* nsq    = hdr + 16;
    int*   off    = (int*)(hdr + 32);
    int*   idx    = (int*)(hdr + 64);
    float* S_part = hdr + 64 + B_SZ;

    codi_setup<<<1, 640, 0, stream>>>(labels, idx, off, SSQ, nsq);
    codi_gather<<<K_LAB * NCHUNK * PS, NTHR, 0, stream>>>(
        z4, idx, off, (float4*)S_part, SSQ);
    codi_reduce<<<(K_LAB * CH) / NTHR, NTHR, 0, stream>>>(S_part, nsq);
    codi_final<<<1, 64, 0, stream>>>(off, SSQ, nsq, (float*)d_out);
}

// Round 5
// 279.150 us; speedup vs baseline: 1.0790x; 1.0790x over previous
//
#include <hip/hip_runtime.h>

// Problem constants (fixed by setup_inputs)
#define B_SZ   8192
#define CH     5120          // C*H = 20*256
#define CH4    1280          // CH / 4 (float4 columns per row)
#define K_LAB  10
#define EPS    1e-8f
#define FLTMAX 3.402823466e38f

#define NTHR   320           // 5 waves; 320 thr * 4 float4 = full 20 KB row
#define PS     64            // sample sub-partitions per label (grid = 640)
#define RB     3             // rows in flight (12 dwordx4/thread batched)

// loss = sum_{k: n_k>0} (SSQ_k - ||S_k||^2/n_k + n_k*CH*eps^2) / (n_k*CH)
// (2*eps cross-term cancels exactly: sum_{b in k}(z_b - mu_k) == 0)

// ---------------------------------------------------------------------------
// Setup: stage labels in LDS, build per-label ascending index lists.
__global__ __launch_bounds__(640) void codi_setup(
    const int* __restrict__ labels, int* __restrict__ idx,
    int* __restrict__ off, float* __restrict__ SSQ, float* __restrict__ nsq)
{
    __shared__ int lab_s[B_SZ];          // 32 KB
    __shared__ int cnts[K_LAB];
    __shared__ int offs[K_LAB + 1];
    const int tid  = threadIdx.x;
    const int k    = tid >> 6;           // wave index == label
    const int lane = tid & 63;

    const int4* l4 = (const int4*)labels;
    for (int i = tid; i < B_SZ / 4; i += 640) ((int4*)lab_s)[i] = l4[i];
    __syncthreads();

    int cnt = 0;
    for (int b0 = 0; b0 < B_SZ; b0 += 64)
        cnt += __popcll(__ballot(lab_s[b0 + lane] == k));
    if (lane == 0) cnts[k] = cnt;
    __syncthreads();
    if (tid == 0) {
        int a = 0;
        for (int j = 0; j < K_LAB; ++j) { offs[j] = a; a += cnts[j]; }
        offs[K_LAB] = a;
    }
    __syncthreads();

    int base = offs[k];
    const unsigned long long ltmask = (1ULL << lane) - 1ULL;
    for (int b0 = 0; b0 < B_SZ; b0 += 64) {
        int lab = lab_s[b0 + lane];
        unsigned long long m = __ballot(lab == k);
        if (lab == k) idx[base + __popcll(m & ltmask)] = b0 + lane;
        base += __popcll(m);
    }
    if (tid < K_LAB + 1) off[tid] = offs[tid];
    if (tid < K_LAB) { SSQ[tid] = 0.f; nsq[tid] = 0.f; }
}

// ---------------------------------------------------------------------------
// Main: block = (label k, sample sub-range); block reads ENTIRE rows (20 KB
// contiguous granule), 3 rows (12 indep dwordx4/thread) pipelined.
__global__ __launch_bounds__(NTHR) void codi_gather(
    const float4* __restrict__ z4, const int* __restrict__ idx,
    const int* __restrict__ off, float4* __restrict__ S_part,
    float* __restrict__ SSQ)
{
    const int tid = threadIdx.x;
    const int k   = blockIdx.x / PS;
    const int ps  = blockIdx.x % PS;

    const int kb  = off[k];
    const int cnt = off[k + 1] - kb;
    const int s0  = kb + (int)(((long long)cnt * ps) / PS);
    const int s1  = kb + (int)(((long long)cnt * (ps + 1)) / PS);
    const int n   = s1 - s0;             // <= 128 even in worst case

    __shared__ int rows[160];
    for (int i = tid; i < n; i += NTHR) rows[i] = idx[s0 + i];
    __syncthreads();

    float4 sum[4];
    #pragma unroll
    for (int j = 0; j < 4; ++j) sum[j] = make_float4(0.f, 0.f, 0.f, 0.f);
    float ssq = 0.f;

#define SANITIZE(v) do { \
        v.x = (v.x == v.x) ? fminf(fmaxf(v.x, -FLTMAX), FLTMAX) : 0.f; \
        v.y = (v.y == v.y) ? fminf(fmaxf(v.y, -FLTMAX), FLTMAX) : 0.f; \
        v.z = (v.z == v.z) ? fminf(fmaxf(v.z, -FLTMAX), FLTMAX) : 0.f; \
        v.w = (v.w == v.w) ? fminf(fmaxf(v.w, -FLTMAX), FLTMAX) : 0.f; \
    } while (0)
#define ACCUM(j, v) do { \
        sum[j].x += v.x; sum[j].y += v.y; sum[j].z += v.z; sum[j].w += v.w; \
        ssq = fmaf(v.x, v.x, ssq); ssq = fmaf(v.y, v.y, ssq); \
        ssq = fmaf(v.z, v.z, ssq); ssq = fmaf(v.w, v.w, ssq); \
    } while (0)

    const int n_main = n - (n % RB);
    for (int i0 = 0; i0 < n_main; i0 += RB) {
        float4 vb[RB][4];
        #pragma unroll
        for (int u = 0; u < RB; ++u) {
            const size_t rbase = (size_t)rows[i0 + u] * CH4;
            #pragma unroll
            for (int j = 0; j < 4; ++j)
                vb[u][j] = z4[rbase + j * NTHR + tid];   // 12 indep dwordx4
        }
        #pragma unroll
        for (int u = 0; u < RB; ++u)
            #pragma unroll
            for (int j = 0; j < 4; ++j) { SANITIZE(vb[u][j]); ACCUM(j, vb[u][j]); }
    }
    for (int i = n_main; i < n; ++i) {   // tail: <= 2 rows, 4-deep MLP each
        const size_t rbase = (size_t)rows[i] * CH4;
        float4 vb[4];
        #pragma unroll
        for (int j = 0; j < 4; ++j) vb[j] = z4[rbase + j * NTHR + tid];
        #pragma unroll
        for (int j = 0; j < 4; ++j) { SANITIZE(vb[j]); ACCUM(j, vb[j]); }
    }
#undef SANITIZE
#undef ACCUM

    // flush: private partial row-sum slice (coalesced float4, 20 KB/block)
    float4* sp = S_part + (size_t)blockIdx.x * CH4;
    #pragma unroll
    for (int j = 0; j < 4; ++j) sp[j * NTHR + tid] = sum[j];

    #pragma unroll
    for (int o = 32; o > 0; o >>= 1) ssq += __shfl_down(ssq, o, 64);
    if ((tid & 63) == 0) atomicAdd(&SSQ[k], ssq);
}

// ---------------------------------------------------------------------------
// Fold PS partials straight into ||S_k||^2. Block (k, cc): 320 float4 cols,
// contiguous 5 KB wave-spans per partial, 64 independent iterations.
__global__ __launch_bounds__(NTHR) void codi_reduce(
    const float4* __restrict__ S_part, float* __restrict__ nsq)
{
    const int tid = threadIdx.x;
    const int k   = blockIdx.x >> 2;     // 40 blocks = 10 k * 4 col-chunks
    const int cc  = blockIdx.x & 3;
    float4 s = make_float4(0.f, 0.f, 0.f, 0.f);
    #pragma unroll 8
    for (int ps = 0; ps < PS; ++ps) {
        float4 v = S_part[((size_t)(k * PS + ps)) * CH4 + cc * NTHR + tid];
        s.x += v.x; s.y += v.y; s.z += v.z; s.w += v.w;
    }
    float w = fmaf(s.x, s.x, fmaf(s.y, s.y, fmaf(s.z, s.z, s.w * s.w)));
    #pragma unroll
    for (int o = 32; o > 0; o >>= 1) w += __shfl_down(w, o, 64);
    if ((tid & 63) == 0) atomicAdd(&nsq[k], w);
}

__global__ __launch_bounds__(64) void codi_final(
    const int* __restrict__ off, const float* __restrict__ SSQ,
    const float* __restrict__ nsq, float* __restrict__ out)
{
    if (threadIdx.x == 0) {
        float loss = 0.f;
        for (int k = 0; k < K_LAB; ++k) {
            float n = (float)(off[k + 1] - off[k]);
            if (n > 0.f) {
                float sse = SSQ[k] - nsq[k] / n + n * (float)CH * (EPS * EPS);
                float mse = sse / (n * (float)CH);
                if (mse == mse) loss += mse;     // nan_to_num(mse_k)
            }
        }
        out[0] = loss;
    }
}

// ---------------------------------------------------------------------------
extern "C" void kernel_launch(void* const* d_in, const int* in_sizes, int n_in,
                              void* d_out, int out_size, void* d_ws, size_t ws_size,
                              hipStream_t stream) {
    const float4* z4     = (const float4*)d_in[0];
    const int*    labels = (const int*)d_in[1];

    // ws layout (floats): [0..9] SSQ, [16..25] nsq, [32..47] off[11],
    //                     [64..8255] idx[8192], [8256..] S_part[640][1280]f4
    float* hdr    = (float*)d_ws;
    float* SSQ    = hdr;
    float* nsq    = hdr + 16;
    int*   off    = (int*)(hdr + 32);
    int*   idx    = (int*)(hdr + 64);
    float* S_part = hdr + 64 + B_SZ;     // byte offset 33024, 16B-aligned

    codi_setup<<<1, 640, 0, stream>>>(labels, idx, off, SSQ, nsq);
    codi_gather<<<K_LAB * PS, NTHR, 0, stream>>>(
        z4, idx, off, (float4*)S_part, SSQ);
    codi_reduce<<<K_LAB * 4, NTHR, 0, stream>>>((const float4*)S_part, nsq);
    codi_final<<<1, 64, 0, stream>>>(off, SSQ, nsq, (float*)d_out);
}

// Round 6
// 268.570 us; speedup vs baseline: 1.1215x; 1.0394x over previous
//
#include <hip/hip_runtime.h>

// Problem constants (fixed by setup_inputs)
#define B_SZ   8192
#define CH     5120          // C*H = 20*256
#define CH4    1280          // CH / 4 (float4 columns per row)
#define K_LAB  10
#define EPS    1e-8f
#define FLTMAX 3.402823466e38f

#define NTHR   320           // 5 waves; 320 thr * 4 float4 = full 20 KB row
#define PS     64            // sample sub-partitions per label (grid = 640)
#define ST     2             // rows per pipeline stage (8 dwordx4 per issue)

// loss = sum_{k: n_k>0} (SSQ_k - ||S_k||^2/n_k + n_k*CH*eps^2) / (n_k*CH)
// (2*eps cross-term cancels exactly: sum_{b in k}(z_b - mu_k) == 0)

// ---------------------------------------------------------------------------
// Setup: stage labels in LDS, build per-label ascending index lists.
__global__ __launch_bounds__(640) void codi_setup(
    const int* __restrict__ labels, int* __restrict__ idx,
    int* __restrict__ off, float* __restrict__ SSQ, float* __restrict__ nsq,
    int* __restrict__ done)
{
    __shared__ int lab_s[B_SZ];          // 32 KB
    __shared__ int cnts[K_LAB];
    __shared__ int offs[K_LAB + 1];
    const int tid  = threadIdx.x;
    const int k    = tid >> 6;           // wave index == label
    const int lane = tid & 63;

    const int4* l4 = (const int4*)labels;
    for (int i = tid; i < B_SZ / 4; i += 640) ((int4*)lab_s)[i] = l4[i];
    __syncthreads();

    int cnt = 0;
    for (int b0 = 0; b0 < B_SZ; b0 += 64)
        cnt += __popcll(__ballot(lab_s[b0 + lane] == k));
    if (lane == 0) cnts[k] = cnt;
    __syncthreads();
    if (tid == 0) {
        int a = 0;
        for (int j = 0; j < K_LAB; ++j) { offs[j] = a; a += cnts[j]; }
        offs[K_LAB] = a;
    }
    __syncthreads();

    int base = offs[k];
    const unsigned long long ltmask = (1ULL << lane) - 1ULL;
    for (int b0 = 0; b0 < B_SZ; b0 += 64) {
        int lab = lab_s[b0 + lane];
        unsigned long long m = __ballot(lab == k);
        if (lab == k) idx[base + __popcll(m & ltmask)] = b0 + lane;
        base += __popcll(m);
    }
    if (tid < K_LAB + 1) off[tid] = offs[tid];
    if (tid < K_LAB) { SSQ[tid] = 0.f; nsq[tid] = 0.f; }
    if (tid == 0) *done = 0;
}

// ---------------------------------------------------------------------------
// Main: block = (label k, sample sub-range); whole-row 20 KB granules.
// Ping-pong pipeline: issue stage s+1 before consuming stage s, so vmem
// requests never drain to zero. Tail is branch-free (clamp + 0/1 weight).
__global__ __launch_bounds__(NTHR) void codi_gather(
    const float4* __restrict__ z4, const int* __restrict__ idx,
    const int* __restrict__ off, float4* __restrict__ S_part,
    float* __restrict__ SSQ)
{
    const int tid = threadIdx.x;
    const int k   = blockIdx.x / PS;
    const int ps  = blockIdx.x % PS;

    const int kb  = off[k];
    const int cnt = off[k + 1] - kb;
    const int s0  = kb + (int)(((long long)cnt * ps) / PS);
    const int s1  = kb + (int)(((long long)cnt * (ps + 1)) / PS);
    const int n   = s1 - s0;

    __shared__ int rows[160];
    for (int i = tid; i < n; i += NTHR) rows[i] = idx[s0 + i];
    __syncthreads();

    float4 sum[4];
    #pragma unroll
    for (int j = 0; j < 4; ++j) sum[j] = make_float4(0.f, 0.f, 0.f, 0.f);
    float ssq = 0.f;

#define ISSUE(BUF, W, S_) do { \
        _Pragma("unroll") \
        for (int u = 0; u < ST; ++u) { \
            int i_ = (S_) * ST + u; \
            int ic_ = (i_ < n) ? i_ : n - 1; \
            W[u] = (i_ < n) ? 1.f : 0.f; \
            const size_t rb_ = (size_t)rows[ic_] * CH4; \
            _Pragma("unroll") \
            for (int j = 0; j < 4; ++j) BUF[u][j] = z4[rb_ + j * NTHR + tid]; \
        } } while (0)

#define CONSUME(BUF, W) do { \
        _Pragma("unroll") \
        for (int u = 0; u < ST; ++u) { \
            _Pragma("unroll") \
            for (int j = 0; j < 4; ++j) { \
                float4 v = BUF[u][j]; \
                v.x = (v.x == v.x) ? fminf(fmaxf(v.x, -FLTMAX), FLTMAX) : 0.f; \
                v.y = (v.y == v.y) ? fminf(fmaxf(v.y, -FLTMAX), FLTMAX) : 0.f; \
                v.z = (v.z == v.z) ? fminf(fmaxf(v.z, -FLTMAX), FLTMAX) : 0.f; \
                v.w = (v.w == v.w) ? fminf(fmaxf(v.w, -FLTMAX), FLTMAX) : 0.f; \
                v.x *= W[u]; v.y *= W[u]; v.z *= W[u]; v.w *= W[u]; \
                sum[j].x += v.x; sum[j].y += v.y; \
                sum[j].z += v.z; sum[j].w += v.w; \
                ssq = fmaf(v.x, v.x, ssq); ssq = fmaf(v.y, v.y, ssq); \
                ssq = fmaf(v.z, v.z, ssq); ssq = fmaf(v.w, v.w, ssq); \
            } \
        } } while (0)

    if (n > 0) {
        const int nst = (n + ST - 1) / ST;
        float4 A[ST][4], B[ST][4];
        float  wa[ST], wb[ST];
        ISSUE(A, wa, 0);
        int s = 0;
        while (s + 1 < nst) {
            ISSUE(B, wb, s + 1);
            CONSUME(A, wa);
            if (s + 2 < nst) ISSUE(A, wa, s + 2);
            CONSUME(B, wb);
            s += 2;
        }
        if (s < nst) CONSUME(A, wa);   // odd stage count: A issued, not consumed
    }
#undef ISSUE
#undef CONSUME

    // flush: private partial row-sum slice (coalesced float4, 20 KB/block)
    float4* sp = S_part + (size_t)blockIdx.x * CH4;
    #pragma unroll
    for (int j = 0; j < 4; ++j) sp[j * NTHR + tid] = sum[j];

    #pragma unroll
    for (int o = 32; o > 0; o >>= 1) ssq += __shfl_down(ssq, o, 64);
    if ((tid & 63) == 0) atomicAdd(&SSQ[k], ssq);
}

// ---------------------------------------------------------------------------
// Fold PS partials into ||S_k||^2; last-finishing block computes the loss
// (threadfence + atomic counter), saving a separate final launch.
__global__ __launch_bounds__(NTHR) void codi_reduce(
    const float4* __restrict__ S_part, float* __restrict__ nsq,
    const float* __restrict__ SSQ, const int* __restrict__ off,
    int* __restrict__ done, float* __restrict__ out)
{
    const int tid = threadIdx.x;
    const int k   = blockIdx.x >> 2;     // 40 blocks = 10 k * 4 col-chunks
    const int cc  = blockIdx.x & 3;
    __shared__ float wsum[5];

    float4 s = make_float4(0.f, 0.f, 0.f, 0.f);
    #pragma unroll 8
    for (int ps = 0; ps < PS; ++ps) {
        float4 v = S_part[((size_t)(k * PS + ps)) * CH4 + cc * NTHR + tid];
        s.x += v.x; s.y += v.y; s.z += v.z; s.w += v.w;
    }
    float w = fmaf(s.x, s.x, fmaf(s.y, s.y, fmaf(s.z, s.z, s.w * s.w)));
    #pragma unroll
    for (int o = 32; o > 0; o >>= 1) w += __shfl_down(w, o, 64);
    if ((tid & 63) == 0) wsum[tid >> 6] = w;
    __syncthreads();

    if (tid == 0) {
        atomicAdd(&nsq[k], wsum[0] + wsum[1] + wsum[2] + wsum[3] + wsum[4]);
        __threadfence();
        int t = atomicAdd(done, 1);
        if (t == K_LAB * 4 - 1) {        // last block: all nsq adds visible
            float loss = 0.f;
            for (int kk = 0; kk < K_LAB; ++kk) {
                float nn = (float)(off[kk + 1] - off[kk]);
                if (nn > 0.f) {
                    float ns  = atomicAdd(&nsq[kk], 0.f);  // coherent read
                    float sse = SSQ[kk] - ns / nn + nn * (float)CH * (EPS * EPS);
                    float mse = sse / (nn * (float)CH);
                    if (mse == mse) loss += mse;           // nan_to_num(mse_k)
                }
            }
            out[0] = loss;
        }
    }
}

// ---------------------------------------------------------------------------
extern "C" void kernel_launch(void* const* d_in, const int* in_sizes, int n_in,
                              void* d_out, int out_size, void* d_ws, size_t ws_size,
                              hipStream_t stream) {
    const float4* z4     = (const float4*)d_in[0];
    const int*    labels = (const int*)d_in[1];

    // ws layout (floats): [0..9] SSQ, [16..25] nsq, [32..42] off[11],
    //                     [48] done, [64..8255] idx[8192], [8256..] S_part
    float* hdr    = (float*)d_ws;
    float* SSQ    = hdr;
    float* nsq    = hdr + 16;
    int*   off    = (int*)(hdr + 32);
    int*   done   = (int*)(hdr + 48);
    int*   idx    = (int*)(hdr + 64);
    float* S_part = hdr + 64 + B_SZ;     // byte offset 33024, 16B-aligned

    codi_setup<<<1, 640, 0, stream>>>(labels, idx, off, SSQ, nsq, done);
    codi_gather<<<K_LAB * PS, NTHR, 0, stream>>>(
        z4, idx, off, (float4*)S_part, SSQ);
    codi_reduce<<<K_LAB * 4, NTHR, 0, stream>>>(
        (const float4*)S_part, nsq, SSQ, off, done, (float*)d_out);
}